// Round 1
// baseline (86.904 us; speedup 1.0000x reference)
//
#include <hip/hip_runtime.h>
#include <hip/hip_bf16.h>

typedef __attribute__((ext_vector_type(8))) __bf16 bf16x8;
typedef __attribute__((ext_vector_type(4))) float  f32x4;

constexpr int NN   = 2048;  // points per batch
constexpr int DD   = 128;   // dim
constexpr int TI   = 128;   // i-tile rows per block
constexpr int TJ   = 64;    // j-tile rows per block
constexpr int LDSS = 136;   // LDS row stride in bf16 elems (128 + 8 pad -> bank-conflict-free)

__global__ __launch_bounds__(256, 2)
void edm_kernel(const float* __restrict__ x, float* __restrict__ out) {
    __shared__ __align__(16) __bf16 As[TI * LDSS];
    __shared__ __align__(16) __bf16 Bs[TJ * LDSS];
    __shared__ float sqA[TI];
    __shared__ float sqB[TJ];

    const int t  = threadIdx.x;
    const int jt = blockIdx.x;   // 0..31  (j tile of 64)
    const int it = blockIdx.y;   // 0..15  (i tile of 128)
    const int b  = blockIdx.z;   // 0..3

    const float* xb = x + (size_t)b * NN * DD;

    // ---- stage A tile: 128 rows x 128 dims, fp32 -> bf16 ----
    // piece = 8 floats; 16 pieces/row; 2048 pieces / 256 threads = 8 iters
    {
        const float* src = xb + (size_t)it * TI * DD;
        #pragma unroll
        for (int iter = 0; iter < 8; ++iter) {
            const int idx = t + iter * 256;
            const int row = idx >> 4;
            const int c16 = idx & 15;
            const float4* p = (const float4*)(src + row * DD + c16 * 8);
            const float4 v0 = p[0];
            const float4 v1 = p[1];
            bf16x8 w;
            w[0] = (__bf16)v0.x; w[1] = (__bf16)v0.y;
            w[2] = (__bf16)v0.z; w[3] = (__bf16)v0.w;
            w[4] = (__bf16)v1.x; w[5] = (__bf16)v1.y;
            w[6] = (__bf16)v1.z; w[7] = (__bf16)v1.w;
            *(bf16x8*)&As[row * LDSS + c16 * 8] = w;
        }
        // ---- stage B tile: 64 rows ----
        const float* srcB = xb + (size_t)jt * TJ * DD;
        #pragma unroll
        for (int iter = 0; iter < 4; ++iter) {
            const int idx = t + iter * 256;
            const int row = idx >> 4;
            const int c16 = idx & 15;
            const float4* p = (const float4*)(srcB + row * DD + c16 * 8);
            const float4 v0 = p[0];
            const float4 v1 = p[1];
            bf16x8 w;
            w[0] = (__bf16)v0.x; w[1] = (__bf16)v0.y;
            w[2] = (__bf16)v0.z; w[3] = (__bf16)v0.w;
            w[4] = (__bf16)v1.x; w[5] = (__bf16)v1.y;
            w[6] = (__bf16)v1.z; w[7] = (__bf16)v1.w;
            *(bf16x8*)&Bs[row * LDSS + c16 * 8] = w;
        }
    }
    __syncthreads();

    // ---- per-row squared norms from the bf16-rounded values (fp32 accumulate)
    // so the diagonal sq_i + sq_i - 2*cross_ii cancels to ~0 like the reference.
    if (t < TI + TJ) {
        const __bf16* r = (t < TI) ? &As[t * LDSS] : &Bs[(t - TI) * LDSS];
        float s = 0.f;
        #pragma unroll
        for (int k = 0; k < DD; k += 8) {
            bf16x8 v = *(const bf16x8*)(r + k);
            #pragma unroll
            for (int j = 0; j < 8; ++j) { const float f = (float)v[j]; s += f * f; }
        }
        if (t < TI) sqA[t] = s; else sqB[t - TI] = s;
    }
    __syncthreads();

    // ---- MFMA: wave computes 64x32 sub-tile (4 x 2 frags of 16x16) ----
    const int wave = t >> 6;
    const int lane = t & 63;
    const int wm = (wave >> 1) * 64;   // 0 or 64
    const int wn = (wave & 1) * 32;    // 0 or 32
    const int lm = lane & 15;
    const int q  = lane >> 4;          // quad 0..3

    f32x4 acc[4][2] = {};
    #pragma unroll
    for (int ks = 0; ks < 4; ++ks) {
        const int kb = ks * 32 + q * 8;
        bf16x8 a[4], bb[2];
        #pragma unroll
        for (int mf = 0; mf < 4; ++mf)
            a[mf] = *(const bf16x8*)&As[(wm + mf * 16 + lm) * LDSS + kb];
        #pragma unroll
        for (int nf = 0; nf < 2; ++nf)
            bb[nf] = *(const bf16x8*)&Bs[(wn + nf * 16 + lm) * LDSS + kb];
        #pragma unroll
        for (int mf = 0; mf < 4; ++mf)
            #pragma unroll
            for (int nf = 0; nf < 2; ++nf)
                acc[mf][nf] = __builtin_amdgcn_mfma_f32_16x16x32_bf16(
                    a[mf], bb[nf], acc[mf][nf], 0, 0, 0);
    }

    // ---- epilogue: d = sqrt(max(sqi + sqj - 2*cross, 0) + eps) ----
    // C/D layout (verified): col = lane&15, row = quad*4 + reg
    float* outp = out + ((size_t)b * NN + (size_t)it * TI) * NN + (size_t)jt * TJ;
    #pragma unroll
    for (int mf = 0; mf < 4; ++mf) {
        #pragma unroll
        for (int nf = 0; nf < 2; ++nf) {
            const int col = wn + nf * 16 + lm;
            const float sj = sqB[col];
            #pragma unroll
            for (int r = 0; r < 4; ++r) {
                const int row = wm + mf * 16 + q * 4 + r;
                float d2 = sqA[row] + sj - 2.0f * acc[mf][nf][r];
                d2 = fmaxf(d2, 0.0f);
                outp[(size_t)row * NN + col] = sqrtf(d2 + 1e-7f);
            }
        }
    }
}

extern "C" void kernel_launch(void* const* d_in, const int* in_sizes, int n_in,
                              void* d_out, int out_size, void* d_ws, size_t ws_size,
                              hipStream_t stream) {
    const float* x = (const float*)d_in[0];
    float* out = (float*)d_out;
    dim3 grid(NN / TJ, NN / TI, 4);   // (32, 16, 4)
    edm_kernel<<<grid, dim3(256), 0, stream>>>(x, out);
}